// Round 2
// baseline (1536.052 us; speedup 1.0000x reference)
//
#include <hip/hip_runtime.h>
#include <cstdint>
#include <cstddef>

// Problem dims
#define Nb 128
#define Cc 64
#define Tt 256
#define Vv 25
#define Ss 3
#define Oo 64
#define Rr 8

// ws layout (float offsets)
static constexpr size_t SZ_AT   = (size_t)Ss * Nb * Vv * Vv * Oo;  // A_t[i][n][u][v][o] : 15,360,000
static constexpr size_t OFF_XM  = SZ_AT;
static constexpr size_t SZ_XM   = (size_t)Nb * Cc * Vv;            // 204,800
static constexpr size_t OFF_SUM   = OFF_XM + SZ_XM;
static constexpr size_t OFF_SUMSQ = OFF_SUM + 64;
static constexpr size_t OFF_MEAN  = OFF_SUMSQ + 64;
static constexpr size_t OFF_RSTD  = OFF_MEAN + 64;

// ---------------- kernel 1: xm = x.mean(axis=T) ----------------
// grid = N*C blocks, 256 threads (= T). thread t reads x[n,c,t,0..24].
__global__ __launch_bounds__(256) void k_xm(const float* __restrict__ x,
                                            float* __restrict__ xm) {
  const int bid = blockIdx.x;          // n*64 + c
  const int tid = threadIdx.x;         // = t
  const float* xp = x + ((size_t)bid * Tt + tid) * Vv;
  float acc[25];
#pragma unroll
  for (int v = 0; v < 25; ++v) acc[v] = xp[v];
#pragma unroll
  for (int v = 0; v < 25; ++v) {
    acc[v] += __shfl_xor(acc[v], 1);
    acc[v] += __shfl_xor(acc[v], 2);
    acc[v] += __shfl_xor(acc[v], 4);
    acc[v] += __shfl_xor(acc[v], 8);
    acc[v] += __shfl_xor(acc[v], 16);
    acc[v] += __shfl_xor(acc[v], 32);
  }
  __shared__ float part[4][25];
  const int lane = tid & 63, wid = tid >> 6;
  if (lane == 0) {
#pragma unroll
    for (int v = 0; v < 25; ++v) part[wid][v] = acc[v];
  }
  __syncthreads();
  if (tid < 25)
    xm[(size_t)bid * 25 + tid] =
        (part[0][tid] + part[1][tid] + part[2][tid] + part[3][tid]) * (1.0f / 256.0f);
}

// ---------------- kernel 2: A_t[i][n][u][v][o] = alpha*(conv3(tanh(x1u - x2v))) + PA ---
// grid = S*N = 384 blocks, 256 threads.
__global__ __launch_bounds__(256) void k_aff(
    const float* __restrict__ xm,
    const float* __restrict__ w1, const float* __restrict__ b1,
    const float* __restrict__ w2, const float* __restrict__ b2,
    const float* __restrict__ w3, const float* __restrict__ b3,
    const float* __restrict__ PA, const float* __restrict__ alpha_p,
    float* __restrict__ At) {
  const int i = blockIdx.x >> 7;   // 0..2
  const int n = blockIdx.x & 127;
  const int tid = threadIdx.x;
  const float alpha = alpha_p[0];

  __shared__ float xm_s[Cc * Vv];          // 1600
  __shared__ float w1_s[Rr * Cc], w2_s[Rr * Cc];
  __shared__ float w3t_s[Rr * 64];         // [r][o]
  __shared__ float x1_s[Rr * Vv], x2_s[Rr * Vv];
  __shared__ float aff_s[Rr * Vv * Vv];    // 5000
  __shared__ float pa_s[Vv * Vv];

  for (int idx = tid; idx < Cc * Vv; idx += 256) xm_s[idx] = xm[(size_t)n * Cc * Vv + idx];
  for (int idx = tid; idx < Rr * Cc; idx += 256) {
    w1_s[idx] = w1[i * Rr * Cc + idx];
    w2_s[idx] = w2[i * Rr * Cc + idx];
  }
  for (int idx = tid; idx < Oo * Rr; idx += 256)
    w3t_s[(idx & 7) * 64 + (idx >> 3)] = w3[i * Oo * Rr + idx];  // transpose to [r][o]
  for (int idx = tid; idx < Vv * Vv; idx += 256) pa_s[idx] = PA[i * Vv * Vv + idx];
  __syncthreads();

  if (tid < Rr * Vv) {
    const int r = tid / 25, v = tid - r * 25;
    float a1 = b1[i * Rr + r], a2 = b2[i * Rr + r];
    for (int c = 0; c < Cc; ++c) {
      const float xv = xm_s[c * 25 + v];
      a1 = fmaf(w1_s[r * 64 + c], xv, a1);
      a2 = fmaf(w2_s[r * 64 + c], xv, a2);
    }
    x1_s[tid] = a1;
    x2_s[tid] = a2;
  }
  __syncthreads();
  for (int idx = tid; idx < Rr * Vv * Vv; idx += 256) {
    const int r = idx / 625, rem = idx - r * 625;
    const int u = rem / 25, v = rem - u * 25;
    aff_s[idx] = tanhf(x1_s[r * 25 + u] - x2_s[r * 25 + v]);
  }
  __syncthreads();
  const size_t base = (size_t)(i * 128 + n) * 40000;  // 25*25*64
  for (int idx = tid; idx < 40000; idx += 256) {
    const int o = idx & 63, uv = idx >> 6;
    float acc = b3[i * 64 + o];
#pragma unroll
    for (int r = 0; r < Rr; ++r) acc = fmaf(w3t_s[r * 64 + o], aff_s[r * 625 + uv], acc);
    At[base + idx] = fmaf(acc, alpha, pa_s[uv]);   // *alpha + PA
  }
}

// ---------------- kernel 3 (heavy): y = sum_i z_i, + BN partial sums -------------
// grid = N * (T/4) = 8192 blocks; 256 threads: thread = (o = tid&63, tl = tid>>6).
__global__ __launch_bounds__(256) void k_main(
    const float* __restrict__ x, const float* __restrict__ wres,
    const float* __restrict__ bres, const float* __restrict__ At,
    float* __restrict__ y, float* __restrict__ gsum, float* __restrict__ gsq) {
  const int n  = blockIdx.x >> 6;
  const int tb = blockIdx.x & 63;
  const int t0 = tb * 4;
  const int tid = threadIdx.x;
  const int o  = tid & 63;
  const int tl = tid >> 6;

  __shared__ __align__(16) float xs[Cc * 112];  // [c][tl*28 + v], 28-pad rows (16B aligned)
  __shared__ float wres_s[64 * 65];             // [o][c], +1 pad
  __shared__ float bn1[256], bn2[256];

  // stage x[n, :, t0..t0+3, :] into LDS (coalesced: 100-float runs per c)
  {
    const float* xb = x + ((size_t)n * Cc * Tt + t0) * Vv;
    for (int idx = tid; idx < Cc * 100; idx += 256) {
      const int c = idx / 100, j = idx - c * 100;
      const int tli = j / 25, v = j - tli * 25;
      xs[c * 112 + tli * 28 + v] = xb[(size_t)c * Tt * Vv + j];
    }
  }

  float z[25];
#pragma unroll
  for (int u = 0; u < 25; ++u) z[u] = 0.0f;

  for (int i = 0; i < Ss; ++i) {
    __syncthreads();   // xs ready (i=0) / previous iter done
    for (int idx = tid; idx < 4096; idx += 256)
      wres_s[(idx >> 6) * 65 + (idx & 63)] = wres[i * 4096 + idx];
    __syncthreads();

    // r[v] = bres + sum_c wres[o,c] * x[n,c,t,v]
    float r[25];
    const float br = bres[i * 64 + o];
#pragma unroll
    for (int v = 0; v < 25; ++v) r[v] = br;

    const float* xrow = xs + tl * 28;
    for (int c = 0; c < Cc; ++c) {
      const float w = wres_s[o * 65 + c];           // 2-way bank, free
      const float* xc = xrow + c * 112;             // broadcast across lanes
      float xv[28];
#pragma unroll
      for (int q = 0; q < 7; ++q)
        *reinterpret_cast<float4*>(&xv[4 * q]) = *reinterpret_cast<const float4*>(xc + 4 * q);
#pragma unroll
      for (int v = 0; v < 25; ++v) r[v] = fmaf(w, xv[v], r[v]);
    }

    // z[u] += sum_v A_t[i][n][u][v][o] * r[v]   (lane-coalesced global loads, L1-reused)
    const float* Ab = At + (size_t)(i * 128 + n) * 40000 + o;
#pragma unroll
    for (int u = 0; u < 25; ++u) {
      float acc = z[u];
#pragma unroll
      for (int v = 0; v < 25; ++v) acc = fmaf(Ab[(u * 25 + v) * 64], r[v], acc);
      z[u] = acc;
    }
  }

  // BN partial sums per channel o
  float s1 = 0.0f, s2 = 0.0f;
#pragma unroll
  for (int u = 0; u < 25; ++u) {
    s1 += z[u];
    s2 = fmaf(z[u], z[u], s2);
  }
  bn1[tl * 64 + o] = s1;
  bn2[tl * 64 + o] = s2;
  __syncthreads();
  if (tid < 64) {
    atomicAdd(&gsum[tid], bn1[tid] + bn1[tid + 64] + bn1[tid + 128] + bn1[tid + 192]);
    atomicAdd(&gsq[tid],  bn2[tid] + bn2[tid + 64] + bn2[tid + 128] + bn2[tid + 192]);
  }

  // stage z via LDS (reuse xs) for coalesced y writes
  float* zs = xs;
#pragma unroll
  for (int u = 0; u < 25; ++u) zs[o * 101 + tl * 25 + u] = z[u];
  __syncthreads();
  const size_t ybase = (size_t)n * 64 * 6400 + (size_t)t0 * 25;
  for (int idx = tid; idx < 6400; idx += 256) {
    const int o2 = idx / 100, j = idx - o2 * 100;
    y[ybase + (size_t)o2 * 6400 + j] = zs[o2 * 101 + j];
  }
}

// ---------------- kernel 4: finalize BN stats ----------------
__global__ void k_stats(const float* __restrict__ gsum, const float* __restrict__ gsq,
                        float* __restrict__ mean, float* __restrict__ rstd) {
  const int o = threadIdx.x;
  const float M = (float)Nb * (float)Tt * (float)Vv;  // 819200
  const float m = gsum[o] / M;
  const float var = gsq[o] / M - m * m;
  mean[o] = m;
  rstd[o] = rsqrtf(var + 1e-5f);
}

// ---------------- kernel 5: epilogue, in-place on y(=d_out): BN + beta/gamma + x + relu
__global__ __launch_bounds__(256) void k_out(
    float* __restrict__ y, const float* __restrict__ x,
    const float* __restrict__ mean, const float* __restrict__ rstd,
    const float* __restrict__ gamma, const float* __restrict__ beta) {
  const size_t total4 = (size_t)Nb * Oo * Tt * Vv / 4;  // 13,107,200
  for (size_t i = (size_t)blockIdx.x * blockDim.x + threadIdx.x; i < total4;
       i += (size_t)gridDim.x * blockDim.x) {
    float4 yv = reinterpret_cast<float4*>(y)[i];
    const float4 xv = reinterpret_cast<const float4*>(x)[i];
    const int o = (int)((i / 1600) & 63);   // 1600 float4 per (n,o)
    const float m = mean[o], rs = rstd[o], g = gamma[o], b = beta[o];
    const float grs = g * rs;
    yv.x = fmaxf(fmaf(grs, yv.x - m, b) + xv.x, 0.0f);
    yv.y = fmaxf(fmaf(grs, yv.y - m, b) + xv.y, 0.0f);
    yv.z = fmaxf(fmaf(grs, yv.z - m, b) + xv.z, 0.0f);
    yv.w = fmaxf(fmaf(grs, yv.w - m, b) + xv.w, 0.0f);
    reinterpret_cast<float4*>(y)[i] = yv;
  }
}

extern "C" void kernel_launch(void* const* d_in, const int* in_sizes, int n_in,
                              void* d_out, int out_size, void* d_ws, size_t ws_size,
                              hipStream_t stream) {
  const float* x     = (const float*)d_in[0];
  const float* w1    = (const float*)d_in[1];
  const float* b1    = (const float*)d_in[2];
  const float* w2    = (const float*)d_in[3];
  const float* b2    = (const float*)d_in[4];
  const float* w3    = (const float*)d_in[5];
  const float* b3    = (const float*)d_in[6];
  const float* wres  = (const float*)d_in[7];
  const float* bres  = (const float*)d_in[8];
  const float* PA    = (const float*)d_in[9];
  const float* alpha = (const float*)d_in[10];
  const float* gamma = (const float*)d_in[11];
  const float* beta  = (const float*)d_in[12];

  float* out = (float*)d_out;
  float* ws  = (float*)d_ws;

  float* At    = ws;             // 15,360,000 floats
  float* xm    = ws + OFF_XM;
  float* gsum  = ws + OFF_SUM;
  float* gsq   = ws + OFF_SUMSQ;
  float* meanp = ws + OFF_MEAN;
  float* rstdp = ws + OFF_RSTD;

  // zero BN accumulators (ws is poisoned before every launch)
  hipMemsetAsync((void*)gsum, 0, 2 * 64 * sizeof(float), stream);

  k_xm<<<Nb * Cc, 256, 0, stream>>>(x, xm);
  k_aff<<<Ss * Nb, 256, 0, stream>>>(xm, w1, b1, w2, b2, w3, b3, PA, alpha, At);
  k_main<<<Nb * (Tt / 4), 256, 0, stream>>>(x, wres, bres, At, out, gsum, gsq);
  k_stats<<<1, 64, 0, stream>>>(gsum, gsq, meanp, rstdp);
  k_out<<<4096, 256, 0, stream>>>(out, x, meanp, rstdp, gamma, beta);
}